// Round 8
// baseline (392.790 us; speedup 1.0000x reference)
//
#include <hip/hip_runtime.h>
#include <hip/hip_bf16.h>
#include <stdint.h>

// Problem constants (fixed by setup_inputs)
#define M_N  16384   // batch rows
#define K_C  2048    // centers
#define DIM  512     // feature dim
#define NCLS 10      // classes
#define NBN  16      // center-blocks (K_C/128) -> split-K partials
#define NBM  (M_N / 128)   // 128 bm slices

typedef unsigned short u16;
typedef float  f32x4  __attribute__((ext_vector_type(4)));
typedef __bf16 bf16x8 __attribute__((ext_vector_type(8)));

// ---- helpers -------------------------------------------------------------

__device__ __forceinline__ void async_ld16(const void* g, void* l) {
  // global -> LDS direct DMA, 16 bytes per lane. LDS dest is wave-uniform
  // base + lane*16 (lds off linear in tid) -- swizzle must be on the SOURCE.
  __builtin_amdgcn_global_load_lds(
      (const __attribute__((address_space(1))) void*)g,
      (__attribute__((address_space(3))) void*)l,
      16, 0, 0);
}

__device__ __forceinline__ u16 f2bf_rne(float f) {
  uint32_t u = __float_as_uint(f);
  u += 0x7FFFu + ((u >> 16) & 1u);
  return (u16)(u >> 16);
}

// ---- kernel 1: prep (batches/centers -> bf16 + norms, W -> bf16, cnt=0) --
// 256 threads. blocks [0, NPREP): two data rows per block.
// last 32 blocks: W fp32 [10][2048] -> bf16 [16][2048]; block NPREP zeroes cnt.

#define NPREP ((M_N + K_C) / 2)

__global__ __launch_bounds__(256) void prep(
    const float4* __restrict__ batches, const float4* __restrict__ centers,
    const float* __restrict__ W,
    ushort4* __restrict__ Abf, ushort4* __restrict__ Bbf,
    float* __restrict__ x2, float* __restrict__ c2, u16* __restrict__ Wbf,
    int* __restrict__ cnt) {
  int b = blockIdx.x, t = threadIdx.x;
  if (b < NPREP) {
    int rp = b * 2 + (t >> 7);          // row index (pair)
    int col = t & 127;
    const float4* src; ushort4* dst; float* sq; int row;
    if (rp < M_N) { src = batches; dst = Abf; sq = x2; row = rp; }
    else          { src = centers; dst = Bbf; sq = c2; row = rp - M_N; }
    float4 v = src[(size_t)row * 128 + col];
    float ss = v.x * v.x + v.y * v.y + v.z * v.z + v.w * v.w;
    ushort4 o;
    o.x = f2bf_rne(v.x); o.y = f2bf_rne(v.y);
    o.z = f2bf_rne(v.z); o.w = f2bf_rne(v.w);
    dst[(size_t)row * 128 + col] = o;
    ss += __shfl_down(ss, 32);
    ss += __shfl_down(ss, 16);
    ss += __shfl_down(ss, 8);
    ss += __shfl_down(ss, 4);
    ss += __shfl_down(ss, 2);
    ss += __shfl_down(ss, 1);
    __shared__ float part[4];
    if ((t & 63) == 0) part[t >> 6] = ss;
    __syncthreads();
    if (t == 0) sq[row] = part[0] + part[1];
    if (t == 128) sq[row] = part[2] + part[3];
  } else {
    int wb = b - NPREP;                 // 32 blocks x 1024 elems
#pragma unroll
    for (int i = 0; i < 4; ++i) {
      int idx = wb * 1024 + i * 256 + t;  // < 16*2048
      int n = idx >> 11, k = idx & 2047;
      Wbf[idx] = (n < NCLS) ? f2bf_rne(W[n * K_C + k]) : (u16)0;
    }
    if (wb == 0 && t < NBM) cnt[t] = 0;   // split-K counters
  }
}

// ---- kernel 2: fused xc-GEMM -> radial -> MFMA (radial@W^T) -> split-K ---
// grid = 2048 blocks, 256 threads (4 waves, 2x2 of 64x64). BK=64.
// XCD swizzle: bid = g*8+r -> bm = r*16 + (g&15), bn = g>>4 (FETCH 85->53 MB).
// partial layout [NBN][M_N][16]: each block stores a CONTIGUOUS 8 KB region
// (R6's [M][bn][16] 64 B fragments caused 4.7x HBM write amplification).
// Last bn-block per bm (device-scope counter) reduces partials + bias -> out.

__global__ __launch_bounds__(256, 4) void rbf_main(
    const u16* __restrict__ A,      // bf16 bits [M_N][DIM]  (batches)
    const u16* __restrict__ B,      // bf16 bits [K_C][DIM]  (centers)
    const float* __restrict__ x2,   // [M_N]
    const float* __restrict__ c2,   // [K_C]
    const float* __restrict__ beta, // [K_C]
    const u16* __restrict__ Wbf,    // bf16 bits [16][K_C]
    const float* __restrict__ bias, // [NCLS]
    float* __restrict__ partial,    // [NBN][M_N][16]
    int* __restrict__ cnt,          // [NBM]
    float* __restrict__ out) {      // [M_N][NCLS]
  constexpr int BK = 64;
  __shared__ alignas(16) unsigned char smem[32768];
  __shared__ int lastFlag;
  u16* As = (u16*)smem;            // batches [128][64] swizzled
  u16* Bs = (u16*)(smem + 16384);  // centers [128][64] swizzled
  u16* Rt = (u16*)smem;            // radial row-major [128][128] swizzled

  const int tid  = threadIdx.x;
  const int lane = tid & 63;
  const int wid  = tid >> 6;
  const int bid = blockIdx.x;
  const int g = bid >> 3, r8 = bid & 7;
  const int bm = r8 * 16 + (g & 15);
  const int bn = g >> 4;
  const int row0 = bm * 128, col0 = bn * 128;
  const int wrC = (wid >> 1) * 64;   // wave CENTER offset in tile
  const int wcB = (wid & 1) * 64;    // wave BATCH offset in tile

  f32x4 acc[4][4] = {};   // acc[mi = center strip][ni = batch strip]

  // staging: thread t -> LDS slot (row=t>>3, s=t&7); loads global chunk
  // g = s ^ (row&7) so LDS[r][c^(r&7)] = global (r, chunk c).
  const int srow = tid >> 3;
  const int scol = ((tid & 7) ^ (srow & 7)) * 8;
  const u16* aG = A + (size_t)(row0 + srow) * DIM + scol;
  const u16* bG = B + (size_t)(col0 + srow) * DIM + scol;
  u16* aL = As + tid * 8;
  u16* bL = Bs + tid * 8;

  const int frow = lane & 15;      // MFMA operand row (m or n)
  const int fq   = lane >> 4;      // k-quarter
  const int fsw  = frow & 7;       // swizzle key

  for (int k0 = 0; k0 < DIM; k0 += BK) {
    __syncthreads();  // previous iter's ds_reads done before overwrite
#pragma unroll
    for (int i = 0; i < 4; ++i) {
      async_ld16(aG + k0 + i * 32 * DIM, aL + i * 2048);
      async_ld16(bG + k0 + i * 32 * DIM, bL + i * 2048);
    }
    __syncthreads();  // vmcnt drained before s_barrier -> tiles ready

#pragma unroll
    for (int kh = 0; kh < 2; ++kh) {
      const int slot = ((kh << 2) | fq) ^ fsw;   // swizzled 16B chunk
      bf16x8 cf[4], bfr[4];
#pragma unroll
      for (int mi = 0; mi < 4; ++mi)   // centers = FIRST operand
        cf[mi] = *(const bf16x8*)(Bs + (wrC + mi * 16 + frow) * BK + slot * 8);
#pragma unroll
      for (int ni = 0; ni < 4; ++ni)   // batches = SECOND operand
        bfr[ni] = *(const bf16x8*)(As + (wcB + ni * 16 + frow) * BK + slot * 8);
#pragma unroll
      for (int mi = 0; mi < 4; ++mi)
#pragma unroll
        for (int ni = 0; ni < 4; ++ni)
          acc[mi][ni] = __builtin_amdgcn_mfma_f32_16x16x32_bf16(
              cf[mi], bfr[ni], acc[mi][ni], 0, 0, 0);
    }
  }

  // ---- epilogue scalars ----
  // D layout: col(lane&15)=batch within 16-strip, row(q*4+reg)=center.
  const int cls = lane & 15, q = lane >> 4;
  float4 c2q[4], btq[4];
#pragma unroll
  for (int mi = 0; mi < 4; ++mi) {
    int base = col0 + wrC + mi * 16 + q * 4;   // 4 consecutive centers
    c2q[mi] = *(const float4*)(c2 + base);
    btq[mi] = *(const float4*)(beta + base);
  }
  float x2v[4];
#pragma unroll
  for (int ni = 0; ni < 4; ++ni)
    x2v[ni] = x2[row0 + wcB + ni * 16 + cls];

  __syncthreads();  // K-loop LDS use finished; smem becomes Rt

  // Rt[br][cc] stored at br*128 + (cc ^ ((br&15)<<3))
  union Pack { u16 h[4]; uint2 v; };
#pragma unroll
  for (int mi = 0; mi < 4; ++mi) {
#pragma unroll
    for (int ni = 0; ni < 4; ++ni) {
      Pack pk;
#pragma unroll
      for (int r = 0; r < 4; ++r) {
        float xc = acc[mi][ni][r];
        float d2 = fmaxf(x2v[ni] + c2q[mi][r] - 2.0f * xc, 0.0f);
        float radial = __expf(-btq[mi][r] * sqrtf(d2));
        pk.h[r] = f2bf_rne(radial);
      }
      int br  = wcB + ni * 16 + cls;           // batch row in tile
      int cc0 = wrC + mi * 16 + q * 4;         // 4 consecutive centers
      *(uint2*)(Rt + br * 128 + (cc0 ^ ((br & 15) << 3))) = pk.v;
    }
  }
  __syncthreads();

  // ---- W fragments (acc dead -> lower peak regs) ----
  bf16x8 wfr[4];
#pragma unroll
  for (int t = 0; t < 4; ++t)
    wfr[t] = *(const bf16x8*)(Wbf + (size_t)cls * K_C + col0 + t * 32 + q * 8);

  // ---- stage 2: out2[128 x 16] = radial[128 x 128] @ W^T via MFMA ----
  f32x4 acc2[2] = {};
#pragma unroll
  for (int s2 = 0; s2 < 2; ++s2) {
    const int br = (wid * 2 + s2) * 16 + cls;
    const u16* rrow = Rt + br * 128;
    const int sw = cls << 3;                   // (br&15)<<3 == cls<<3
#pragma unroll
    for (int t = 0; t < 4; ++t) {
      bf16x8 ra = *(const bf16x8*)(rrow + ((t * 32 + q * 8) ^ sw));
      acc2[s2] = __builtin_amdgcn_mfma_f32_16x16x32_bf16(
          ra, wfr[t], acc2[s2], 0, 0, 0);
    }
  }

  // store: D2 col(lane&15)=class, row(q*4+r)=batch row within strip.
  // [NBN][M_N][16]: this block's 128 rows x 64 B = contiguous 8 KB.
#pragma unroll
  for (int s2 = 0; s2 < 2; ++s2)
#pragma unroll
    for (int r = 0; r < 4; ++r) {
      int gr = row0 + (wid * 2 + s2) * 16 + q * 4 + r;
      partial[((size_t)bn * M_N + gr) * 16 + cls] = acc2[s2][r];
    }

  // ---- split-K: last bn-block for this bm reduces partials -> out ----
  __syncthreads();   // all waves' partial stores issued
  __threadfence();   // device-scope release: stores visible across XCDs
  if (tid == 0) {
    int prev = atomicAdd(&cnt[bm], 1);   // device-scope by default
    lastFlag = (prev == NBN - 1);
  }
  __syncthreads();
  if (!lastFlag) return;
  __threadfence();   // device-scope acquire: see all 16 blocks' partials

  // one wave -> 32 rows; lane: bn-slice = lane>>2, class-quad = lane&3
  const int bnl = lane >> 2, quad = lane & 3;
  float4 bq = {0.f, 0.f, 0.f, 0.f};
  if (quad == 0)      bq = *(const float4*)(bias);
  else if (quad == 1) bq = *(const float4*)(bias + 4);
  else if (quad == 2) { bq.x = bias[8]; bq.y = bias[9]; }
  for (int rr = 0; rr < 32; ++rr) {
    int row = row0 + wid * 32 + rr;
    const float* p = partial + ((size_t)bnl * M_N + row) * 16 + quad * 4;
    float4 v = *(const float4*)p;
#pragma unroll
    for (int m = 4; m < 64; m <<= 1) {
      v.x += __shfl_xor(v.x, m);
      v.y += __shfl_xor(v.y, m);
      v.z += __shfl_xor(v.z, m);
      v.w += __shfl_xor(v.w, m);
    }
    if (lane < 2) {            // classes 0-3 / 4-7
      float* o = out + (size_t)row * NCLS + quad * 4;
      *(float2*)o       = {v.x + bq.x, v.y + bq.y};
      *(float2*)(o + 2) = {v.z + bq.z, v.w + bq.w};
    } else if (lane == 2) {    // classes 8,9
      *(float2*)(out + (size_t)row * NCLS + 8) = {v.x + bq.x, v.y + bq.y};
    }
  }
}

// ---- launch --------------------------------------------------------------

extern "C" void kernel_launch(void* const* d_in, const int* in_sizes, int n_in,
                              void* d_out, int out_size, void* d_ws, size_t ws_size,
                              hipStream_t stream) {
  const float* batches = (const float*)d_in[0];  // [16384,512]
  const float* centers = (const float*)d_in[1];  // [2048,512]
  const float* beta    = (const float*)d_in[2];  // [1,2048]
  const float* W       = (const float*)d_in[3];  // [10,2048]
  const float* bias    = (const float*)d_in[4];  // [10]
  float* out = (float*)d_out;                    // [16384,10]

  char* ws = (char*)d_ws;
  u16*  Abf = (u16*)ws;                                   // 16 MiB
  u16*  Bbf = (u16*)(ws + (size_t)M_N * DIM * 2);         // 2 MiB
  float* x2 = (float*)(ws + (size_t)(M_N + K_C) * DIM * 2);
  float* c2 = x2 + M_N;
  u16*  Wbf = (u16*)(c2 + K_C);                           // 64 KiB
  int*  cnt = (int*)((char*)Wbf + 16 * K_C * 2);          // 512 B
  float* partial = (float*)((char*)cnt + 1024);           // 16.8 MiB

  prep<<<dim3(NPREP + 32), dim3(256), 0, stream>>>(
      (const float4*)batches, (const float4*)centers, W,
      (ushort4*)Abf, (ushort4*)Bbf, x2, c2, Wbf, cnt);
  rbf_main<<<dim3(NBN * NBM), dim3(256), 0, stream>>>(
      Abf, Bbf, x2, c2, beta, Wbf, bias, partial, cnt, out);
}

// Round 9
// 145.819 us; speedup vs baseline: 2.6937x; 2.6937x over previous
//
#include <hip/hip_runtime.h>
#include <hip/hip_bf16.h>
#include <stdint.h>

// Problem constants (fixed by setup_inputs)
#define M_N  16384   // batch rows
#define K_C  2048    // centers
#define DIM  512     // feature dim
#define NCLS 10      // classes
#define NBN  16      // center-blocks (K_C/128) -> split-K partials
#define NBM  (M_N / 128)   // 128 bm slices

typedef unsigned short u16;
typedef float  f32x4  __attribute__((ext_vector_type(4)));
typedef __bf16 bf16x8 __attribute__((ext_vector_type(8)));

// ---- helpers -------------------------------------------------------------

__device__ __forceinline__ void async_ld16(const void* g, void* l) {
  // global -> LDS direct DMA, 16 bytes per lane. LDS dest is wave-uniform
  // base + lane*16 (lds off linear in tid) -- swizzle must be on the SOURCE.
  __builtin_amdgcn_global_load_lds(
      (const __attribute__((address_space(1))) void*)g,
      (__attribute__((address_space(3))) void*)l,
      16, 0, 0);
}

__device__ __forceinline__ u16 f2bf_rne(float f) {
  uint32_t u = __float_as_uint(f);
  u += 0x7FFFu + ((u >> 16) & 1u);
  return (u16)(u >> 16);
}

// ---- kernel 1: prep (batches/centers -> bf16 + norms, W -> bf16) ---------
// 256 threads. blocks [0, NPREP): two data rows per block.
// last 32 blocks: W fp32 [10][2048] -> bf16 [16][2048] (rows 10..15 = 0).

#define NPREP ((M_N + K_C) / 2)

__global__ __launch_bounds__(256) void prep(
    const float4* __restrict__ batches, const float4* __restrict__ centers,
    const float* __restrict__ W,
    ushort4* __restrict__ Abf, ushort4* __restrict__ Bbf,
    float* __restrict__ x2, float* __restrict__ c2, u16* __restrict__ Wbf) {
  int b = blockIdx.x, t = threadIdx.x;
  if (b < NPREP) {
    int rp = b * 2 + (t >> 7);          // row index (pair)
    int col = t & 127;
    const float4* src; ushort4* dst; float* sq; int row;
    if (rp < M_N) { src = batches; dst = Abf; sq = x2; row = rp; }
    else          { src = centers; dst = Bbf; sq = c2; row = rp - M_N; }
    float4 v = src[(size_t)row * 128 + col];
    float ss = v.x * v.x + v.y * v.y + v.z * v.z + v.w * v.w;
    ushort4 o;
    o.x = f2bf_rne(v.x); o.y = f2bf_rne(v.y);
    o.z = f2bf_rne(v.z); o.w = f2bf_rne(v.w);
    dst[(size_t)row * 128 + col] = o;
    ss += __shfl_down(ss, 32);
    ss += __shfl_down(ss, 16);
    ss += __shfl_down(ss, 8);
    ss += __shfl_down(ss, 4);
    ss += __shfl_down(ss, 2);
    ss += __shfl_down(ss, 1);
    __shared__ float part[4];
    if ((t & 63) == 0) part[t >> 6] = ss;
    __syncthreads();
    if (t == 0) sq[row] = part[0] + part[1];
    if (t == 128) sq[row] = part[2] + part[3];
  } else {
    int wb = b - NPREP;                 // 32 blocks x 1024 elems
#pragma unroll
    for (int i = 0; i < 4; ++i) {
      int idx = wb * 1024 + i * 256 + t;  // < 16*2048
      int n = idx >> 11, k = idx & 2047;
      Wbf[idx] = (n < NCLS) ? f2bf_rne(W[n * K_C + k]) : (u16)0;
    }
  }
}

// ---- kernel 2: fused xc-GEMM -> radial -> MFMA (radial@W^T) --------------
// grid = 2048 blocks, 256 threads (4 waves, 2x2 of 64x64). BK=64.
// XCD swizzle: bid = g*8+r -> bm = r*16 + (g&15), bn = g>>4 (FETCH 85->53 MB).
// partial layout [NBN][M_N][16]: each block stores a CONTIGUOUS 8 KB region
// (R6's [M][bn][16] 64 B fragments caused 4.7x HBM write amplification).
// NO split-K fusion: device-scope fences per block flush XCD L2s (R8:
// 311 us, MfmaUtil 4.6%) -- the kernel boundary is the cheap fence.

__global__ __launch_bounds__(256, 4) void rbf_main(
    const u16* __restrict__ A,      // bf16 bits [M_N][DIM]  (batches)
    const u16* __restrict__ B,      // bf16 bits [K_C][DIM]  (centers)
    const float* __restrict__ x2,   // [M_N]
    const float* __restrict__ c2,   // [K_C]
    const float* __restrict__ beta, // [K_C]
    const u16* __restrict__ Wbf,    // bf16 bits [16][K_C]
    float* __restrict__ partial) {  // [NBN][M_N][16]
  constexpr int BK = 64;
  __shared__ alignas(16) unsigned char smem[32768];
  u16* As = (u16*)smem;            // batches [128][64] swizzled
  u16* Bs = (u16*)(smem + 16384);  // centers [128][64] swizzled
  u16* Rt = (u16*)smem;            // radial row-major [128][128] swizzled

  const int tid  = threadIdx.x;
  const int lane = tid & 63;
  const int wid  = tid >> 6;
  const int bid = blockIdx.x;
  const int g = bid >> 3, r8 = bid & 7;
  const int bm = r8 * 16 + (g & 15);
  const int bn = g >> 4;
  const int row0 = bm * 128, col0 = bn * 128;
  const int wrC = (wid >> 1) * 64;   // wave CENTER offset in tile
  const int wcB = (wid & 1) * 64;    // wave BATCH offset in tile

  f32x4 acc[4][4] = {};   // acc[mi = center strip][ni = batch strip]

  // staging: thread t -> LDS slot (row=t>>3, s=t&7); loads global chunk
  // g = s ^ (row&7) so LDS[r][c^(r&7)] = global (r, chunk c).
  const int srow = tid >> 3;
  const int scol = ((tid & 7) ^ (srow & 7)) * 8;
  const u16* aG = A + (size_t)(row0 + srow) * DIM + scol;
  const u16* bG = B + (size_t)(col0 + srow) * DIM + scol;
  u16* aL = As + tid * 8;
  u16* bL = Bs + tid * 8;

  const int frow = lane & 15;      // MFMA operand row (m or n)
  const int fq   = lane >> 4;      // k-quarter
  const int fsw  = frow & 7;       // swizzle key

  for (int k0 = 0; k0 < DIM; k0 += BK) {
    __syncthreads();  // previous iter's ds_reads done before overwrite
#pragma unroll
    for (int i = 0; i < 4; ++i) {
      async_ld16(aG + k0 + i * 32 * DIM, aL + i * 2048);
      async_ld16(bG + k0 + i * 32 * DIM, bL + i * 2048);
    }
    __syncthreads();  // vmcnt drained before s_barrier -> tiles ready

#pragma unroll
    for (int kh = 0; kh < 2; ++kh) {
      const int slot = ((kh << 2) | fq) ^ fsw;   // swizzled 16B chunk
      bf16x8 cf[4], bfr[4];
#pragma unroll
      for (int mi = 0; mi < 4; ++mi)   // centers = FIRST operand
        cf[mi] = *(const bf16x8*)(Bs + (wrC + mi * 16 + frow) * BK + slot * 8);
#pragma unroll
      for (int ni = 0; ni < 4; ++ni)   // batches = SECOND operand
        bfr[ni] = *(const bf16x8*)(As + (wcB + ni * 16 + frow) * BK + slot * 8);
#pragma unroll
      for (int mi = 0; mi < 4; ++mi)
#pragma unroll
        for (int ni = 0; ni < 4; ++ni)
          acc[mi][ni] = __builtin_amdgcn_mfma_f32_16x16x32_bf16(
              cf[mi], bfr[ni], acc[mi][ni], 0, 0, 0);
    }
  }

  // ---- epilogue scalars ----
  // D layout: col(lane&15)=batch within 16-strip, row(q*4+reg)=center.
  const int cls = lane & 15, q = lane >> 4;
  float4 c2q[4], btq[4];
#pragma unroll
  for (int mi = 0; mi < 4; ++mi) {
    int base = col0 + wrC + mi * 16 + q * 4;   // 4 consecutive centers
    c2q[mi] = *(const float4*)(c2 + base);
    btq[mi] = *(const float4*)(beta + base);
  }
  float x2v[4];
#pragma unroll
  for (int ni = 0; ni < 4; ++ni)
    x2v[ni] = x2[row0 + wcB + ni * 16 + cls];

  __syncthreads();  // K-loop LDS use finished; smem becomes Rt

  // Rt[br][cc] stored at br*128 + (cc ^ ((br&15)<<3))
  union Pack { u16 h[4]; uint2 v; };
#pragma unroll
  for (int mi = 0; mi < 4; ++mi) {
#pragma unroll
    for (int ni = 0; ni < 4; ++ni) {
      Pack pk;
#pragma unroll
      for (int r = 0; r < 4; ++r) {
        float xc = acc[mi][ni][r];
        float d2 = fmaxf(x2v[ni] + c2q[mi][r] - 2.0f * xc, 0.0f);
        float radial = __expf(-btq[mi][r] * sqrtf(d2));
        pk.h[r] = f2bf_rne(radial);
      }
      int br  = wcB + ni * 16 + cls;           // batch row in tile
      int cc0 = wrC + mi * 16 + q * 4;         // 4 consecutive centers
      *(uint2*)(Rt + br * 128 + (cc0 ^ ((br & 15) << 3))) = pk.v;
    }
  }
  __syncthreads();

  // ---- W fragments (acc dead -> lower peak regs) ----
  bf16x8 wfr[4];
#pragma unroll
  for (int t = 0; t < 4; ++t)
    wfr[t] = *(const bf16x8*)(Wbf + (size_t)cls * K_C + col0 + t * 32 + q * 8);

  // ---- stage 2: out2[128 x 16] = radial[128 x 128] @ W^T via MFMA ----
  f32x4 acc2[2] = {};
#pragma unroll
  for (int s2 = 0; s2 < 2; ++s2) {
    const int br = (wid * 2 + s2) * 16 + cls;
    const u16* rrow = Rt + br * 128;
    const int sw = cls << 3;                   // (br&15)<<3 == cls<<3
#pragma unroll
    for (int t = 0; t < 4; ++t) {
      bf16x8 ra = *(const bf16x8*)(rrow + ((t * 32 + q * 8) ^ sw));
      acc2[s2] = __builtin_amdgcn_mfma_f32_16x16x32_bf16(
          ra, wfr[t], acc2[s2], 0, 0, 0);
    }
  }

  // store: D2 col(lane&15)=class, row(q*4+r)=batch row within strip.
  // [NBN][M_N][16]: this block's 128 rows x 64 B = contiguous 8 KB.
#pragma unroll
  for (int s2 = 0; s2 < 2; ++s2)
#pragma unroll
    for (int r = 0; r < 4; ++r) {
      int gr = row0 + (wid * 2 + s2) * 16 + q * 4 + r;
      partial[((size_t)bn * M_N + gr) * 16 + cls] = acc2[s2][r];
    }
}

// ---- kernel 3: out[i][:] = b + sum_bn partial[bn][i][:] ------------------
// 4 threads per row (each owns a float4 quad); per bn-slice a wave reads
// 1 KB contiguous. 256 thr = 64 rows/block, grid = 256.

__global__ __launch_bounds__(256) void reduce_out(
    const float* __restrict__ partial, const float* __restrict__ b,
    float* __restrict__ out) {
  int t = threadIdx.x;
  int row = blockIdx.x * 64 + (t >> 2);
  int quad = t & 3;
  float4 v = {0.f, 0.f, 0.f, 0.f};
#pragma unroll
  for (int bn = 0; bn < NBN; ++bn) {
    float4 p = *(const float4*)(partial + ((size_t)bn * M_N + row) * 16 + quad * 4);
    v.x += p.x; v.y += p.y; v.z += p.z; v.w += p.w;
  }
  if (quad == 0) {
    float4 bq = *(const float4*)b;
    float* o = out + (size_t)row * NCLS;
    *(float2*)o       = {v.x + bq.x, v.y + bq.y};
    *(float2*)(o + 2) = {v.z + bq.z, v.w + bq.w};
  } else if (quad == 1) {
    float4 bq = *(const float4*)(b + 4);
    float* o = out + (size_t)row * NCLS + 4;
    *(float2*)o       = {v.x + bq.x, v.y + bq.y};
    *(float2*)(o + 2) = {v.z + bq.z, v.w + bq.w};
  } else if (quad == 2) {
    *(float2*)(out + (size_t)row * NCLS + 8) = {v.x + b[8], v.y + b[9]};
  }
}

// ---- launch --------------------------------------------------------------

extern "C" void kernel_launch(void* const* d_in, const int* in_sizes, int n_in,
                              void* d_out, int out_size, void* d_ws, size_t ws_size,
                              hipStream_t stream) {
  const float* batches = (const float*)d_in[0];  // [16384,512]
  const float* centers = (const float*)d_in[1];  // [2048,512]
  const float* beta    = (const float*)d_in[2];  // [1,2048]
  const float* W       = (const float*)d_in[3];  // [10,2048]
  const float* bias    = (const float*)d_in[4];  // [10]
  float* out = (float*)d_out;                    // [16384,10]

  char* ws = (char*)d_ws;
  u16*  Abf = (u16*)ws;                                   // 16 MiB
  u16*  Bbf = (u16*)(ws + (size_t)M_N * DIM * 2);         // 2 MiB
  float* x2 = (float*)(ws + (size_t)(M_N + K_C) * DIM * 2);
  float* c2 = x2 + M_N;
  u16*  Wbf = (u16*)(c2 + K_C);                           // 64 KiB
  float* partial = (float*)((char*)Wbf + 16 * K_C * 2);   // 16.8 MiB

  prep<<<dim3(NPREP + 32), dim3(256), 0, stream>>>(
      (const float4*)batches, (const float4*)centers, W,
      (ushort4*)Abf, (ushort4*)Bbf, x2, c2, Wbf);
  rbf_main<<<dim3(NBN * NBM), dim3(256), 0, stream>>>(
      Abf, Bbf, x2, c2, beta, Wbf, partial);
  reduce_out<<<dim3(M_N / 64), dim3(256), 0, stream>>>(partial, bias, out);
}

// Round 10
// 136.451 us; speedup vs baseline: 2.8786x; 1.0687x over previous
//
#include <hip/hip_runtime.h>
#include <hip/hip_bf16.h>
#include <stdint.h>

// Problem constants (fixed by setup_inputs)
#define M_N  16384   // batch rows
#define K_C  2048    // centers
#define DIM  512     // feature dim
#define NCLS 10      // classes
#define NBN  16      // center-blocks (K_C/128) -> split-K partials
#define NBM  (M_N / 128)   // 128 bm slices

typedef unsigned short u16;
typedef float  f32x4  __attribute__((ext_vector_type(4)));
typedef __bf16 bf16x8 __attribute__((ext_vector_type(8)));

// ---- helpers -------------------------------------------------------------

__device__ __forceinline__ void async_ld16(const void* g, void* l) {
  // global -> LDS direct DMA, 16 bytes per lane. LDS dest is wave-uniform
  // base + lane*16 (lds off linear in tid) -- swizzle must be on the SOURCE.
  __builtin_amdgcn_global_load_lds(
      (const __attribute__((address_space(1))) void*)g,
      (__attribute__((address_space(3))) void*)l,
      16, 0, 0);
}

__device__ __forceinline__ u16 f2bf_rne(float f) {
  uint32_t u = __float_as_uint(f);
  u += 0x7FFFu + ((u >> 16) & 1u);
  return (u16)(u >> 16);
}

// ---- kernel 1: prep (batches/centers -> bf16 + norms, W -> Wperm bf16) ---
// 256 threads. blocks [0, NPREP): two data rows per block.
// last 32 blocks: W fp32 [10][2048] -> PERMUTED bf16 [16][2048]:
// position p's low 7 bits (h,t,q,j) map to center offset
// h*64 + (2t + (j>>2))*16 + q*4 + (j&3)  -- the order stage-1 accumulator
// registers naturally hold centers, so stage-2 A-frags need NO transpose.

#define NPREP ((M_N + K_C) / 2)

__global__ __launch_bounds__(256) void prep(
    const float4* __restrict__ batches, const float4* __restrict__ centers,
    const float* __restrict__ W,
    ushort4* __restrict__ Abf, ushort4* __restrict__ Bbf,
    float* __restrict__ x2, float* __restrict__ c2, u16* __restrict__ Wperm) {
  int b = blockIdx.x, t = threadIdx.x;
  if (b < NPREP) {
    int rp = b * 2 + (t >> 7);          // row index (pair)
    int col = t & 127;
    const float4* src; ushort4* dst; float* sq; int row;
    if (rp < M_N) { src = batches; dst = Abf; sq = x2; row = rp; }
    else          { src = centers; dst = Bbf; sq = c2; row = rp - M_N; }
    float4 v = src[(size_t)row * 128 + col];
    float ss = v.x * v.x + v.y * v.y + v.z * v.z + v.w * v.w;
    ushort4 o;
    o.x = f2bf_rne(v.x); o.y = f2bf_rne(v.y);
    o.z = f2bf_rne(v.z); o.w = f2bf_rne(v.w);
    dst[(size_t)row * 128 + col] = o;
    ss += __shfl_down(ss, 32);
    ss += __shfl_down(ss, 16);
    ss += __shfl_down(ss, 8);
    ss += __shfl_down(ss, 4);
    ss += __shfl_down(ss, 2);
    ss += __shfl_down(ss, 1);
    __shared__ float part[4];
    if ((t & 63) == 0) part[t >> 6] = ss;
    __syncthreads();
    if (t == 0) sq[row] = part[0] + part[1];
    if (t == 128) sq[row] = part[2] + part[3];
  } else {
    int wb = b - NPREP;                 // 32 blocks x 1024 elems
#pragma unroll
    for (int i = 0; i < 4; ++i) {
      int p = wb * 1024 + i * 256 + t;  // < 16*2048
      int cls = p >> 11, k = p & 2047;
      int bn = k >> 7, rem = k & 127;
      int hh = (rem >> 6) & 1, tt = (rem >> 5) & 1;
      int qq = (rem >> 3) & 3, jj = rem & 7;
      int c = bn * 128 + hh * 64 + (tt * 2 + (jj >> 2)) * 16 + qq * 4 + (jj & 3);
      Wperm[p] = (cls < NCLS) ? f2bf_rne(W[cls * K_C + c]) : (u16)0;
    }
  }
}

// ---- kernel 2: fused xc-GEMM -> radial -> MFMA (radial@Wperm^T) ----------
// grid = 2048 blocks, 256 threads (4 waves, 2x2 of 64x64). BK=64.
// XCD swizzle: bid = g*8+r -> bm = r*16 + (g&15), bn = g>>4 (FETCH 85->53 MB).
// Stage-2 A-frags built DIRECTLY from stage-1 accumulators (Wperm matches
// the register order) -- no 32 KB LDS transpose. Wave pairs (wid, wid+2)
// hold the two 64-center halves; summed via 8 KB LDS (unioned on staging).
// partial stores NON-TEMPORAL: written once, read once by reduce_out;
// keeps the XCD's A-slice L2-resident.
// NO split-K fusion: device fences flush XCD L2s (R8: 311 us).

__global__ __launch_bounds__(256, 4) void rbf_main(
    const u16* __restrict__ A,      // bf16 bits [M_N][DIM]  (batches)
    const u16* __restrict__ B,      // bf16 bits [K_C][DIM]  (centers)
    const float* __restrict__ x2,   // [M_N]
    const float* __restrict__ c2,   // [K_C]
    const float* __restrict__ beta, // [K_C]
    const u16* __restrict__ Wperm,  // bf16 bits [16][K_C] permuted
    float* __restrict__ partial) {  // [NBN][M_N][16]
  constexpr int BK = 64;
  __shared__ alignas(16) unsigned char smem[32768];
  u16* As = (u16*)smem;            // batches [128][64] swizzled
  u16* Bs = (u16*)(smem + 16384);  // centers [128][64] swizzled
  f32x4* sumbuf = (f32x4*)smem;    // 8 KB wave-pair sum (after K-loop)

  const int tid  = threadIdx.x;
  const int lane = tid & 63;
  const int wid  = tid >> 6;
  const int bid = blockIdx.x;
  const int g = bid >> 3, r8 = bid & 7;
  const int bm = r8 * 16 + (g & 15);
  const int bn = g >> 4;
  const int row0 = bm * 128, col0 = bn * 128;
  const int wrC = (wid >> 1) * 64;   // wave CENTER offset in tile
  const int wcB = (wid & 1) * 64;    // wave BATCH offset in tile

  f32x4 acc[4][4] = {};   // acc[mi = center strip][ni = batch strip]

  // staging: thread t -> LDS slot (row=t>>3, s=t&7); loads global chunk
  // g = s ^ (row&7) so LDS[r][c^(r&7)] = global (r, chunk c).
  const int srow = tid >> 3;
  const int scol = ((tid & 7) ^ (srow & 7)) * 8;
  const u16* aG = A + (size_t)(row0 + srow) * DIM + scol;
  const u16* bG = B + (size_t)(col0 + srow) * DIM + scol;
  u16* aL = As + tid * 8;
  u16* bL = Bs + tid * 8;

  const int frow = lane & 15;      // MFMA operand row (m or n)
  const int fq   = lane >> 4;      // k-quarter
  const int fsw  = frow & 7;       // swizzle key

  for (int k0 = 0; k0 < DIM; k0 += BK) {
    __syncthreads();  // previous iter's ds_reads done before overwrite
#pragma unroll
    for (int i = 0; i < 4; ++i) {
      async_ld16(aG + k0 + i * 32 * DIM, aL + i * 2048);
      async_ld16(bG + k0 + i * 32 * DIM, bL + i * 2048);
    }
    __syncthreads();  // vmcnt drained before s_barrier -> tiles ready

#pragma unroll
    for (int kh = 0; kh < 2; ++kh) {
      const int slot = ((kh << 2) | fq) ^ fsw;   // swizzled 16B chunk
      bf16x8 cf[4], bfr[4];
#pragma unroll
      for (int mi = 0; mi < 4; ++mi)   // centers = FIRST operand
        cf[mi] = *(const bf16x8*)(Bs + (wrC + mi * 16 + frow) * BK + slot * 8);
#pragma unroll
      for (int ni = 0; ni < 4; ++ni)   // batches = SECOND operand
        bfr[ni] = *(const bf16x8*)(As + (wcB + ni * 16 + frow) * BK + slot * 8);
#pragma unroll
      for (int mi = 0; mi < 4; ++mi)
#pragma unroll
        for (int ni = 0; ni < 4; ++ni)
          acc[mi][ni] = __builtin_amdgcn_mfma_f32_16x16x32_bf16(
              cf[mi], bfr[ni], acc[mi][ni], 0, 0, 0);
    }
  }

  // ---- epilogue: acc (xc) -> radial, IN PLACE ----
  // D layout: col(lane&15)=batch within 16-strip, row(q*4+reg)=center.
  const int cls = lane & 15, q = lane >> 4;
  float4 c2q[4], btq[4];
#pragma unroll
  for (int mi = 0; mi < 4; ++mi) {
    int base = col0 + wrC + mi * 16 + q * 4;   // 4 consecutive centers
    c2q[mi] = *(const float4*)(c2 + base);
    btq[mi] = *(const float4*)(beta + base);
  }
  float x2v[4];
#pragma unroll
  for (int ni = 0; ni < 4; ++ni)
    x2v[ni] = x2[row0 + wcB + ni * 16 + cls];

#pragma unroll
  for (int mi = 0; mi < 4; ++mi)
#pragma unroll
    for (int ni = 0; ni < 4; ++ni)
#pragma unroll
      for (int r = 0; r < 4; ++r) {
        float xc = acc[mi][ni][r];
        float d2 = fmaxf(x2v[ni] + c2q[mi][r] - 2.0f * xc, 0.0f);
        acc[mi][ni][r] = __expf(-btq[mi][r] * sqrtf(d2));
      }

  // ---- stage 2: this wave's 64-center half vs its Wperm half ----
  const int h = wid >> 1;            // which 64-center half
  bf16x8 wfr[2];
#pragma unroll
  for (int t = 0; t < 2; ++t)
    wfr[t] = *(const bf16x8*)(Wperm + (size_t)cls * K_C + col0 + h * 64 +
                              t * 32 + q * 8);

  f32x4 acc2[4] = {};
#pragma unroll
  for (int ni = 0; ni < 4; ++ni) {
#pragma unroll
    for (int t = 0; t < 2; ++t) {
      union { u16 hh[8]; bf16x8 v; } pk;
#pragma unroll
      for (int r = 0; r < 4; ++r) {
        pk.hh[r]     = f2bf_rne(acc[2 * t][ni][r]);
        pk.hh[4 + r] = f2bf_rne(acc[2 * t + 1][ni][r]);
      }
      acc2[ni] = __builtin_amdgcn_mfma_f32_16x16x32_bf16(
          pk.v, wfr[t], acc2[ni], 0, 0, 0);
    }
  }

  // ---- wave-pair sum (wid and wid+2 share batches, split centers) ----
  __syncthreads();   // staging LDS dead; reuse as sumbuf
  if (wid >= 2) {
#pragma unroll
    for (int ni = 0; ni < 4; ++ni)
      sumbuf[((wid & 1) * 4 + ni) * 64 + lane] = acc2[ni];
  }
  __syncthreads();
  if (wid < 2) {
#pragma unroll
    for (int ni = 0; ni < 4; ++ni) {
      f32x4 o = sumbuf[(wid * 4 + ni) * 64 + lane];
      acc2[ni] += o;
      // D2: col(lane&15)=class, row(q*4+r)=batch row within strip.
#pragma unroll
      for (int r = 0; r < 4; ++r) {
        int gr = row0 + wid * 64 + ni * 16 + q * 4 + r;
        __builtin_nontemporal_store(
            acc2[ni][r], &partial[((size_t)bn * M_N + gr) * 16 + cls]);
      }
    }
  }
}

// ---- kernel 3: out[i][:] = b + sum_bn partial[bn][i][:] ------------------
// 4 threads per row (each owns a float4 quad); per bn-slice a wave reads
// 1 KB contiguous. 256 thr = 64 rows/block, grid = 256. nt loads.

__global__ __launch_bounds__(256) void reduce_out(
    const float* __restrict__ partial, const float* __restrict__ b,
    float* __restrict__ out) {
  int t = threadIdx.x;
  int row = blockIdx.x * 64 + (t >> 2);
  int quad = t & 3;
  f32x4 v = {0.f, 0.f, 0.f, 0.f};
#pragma unroll
  for (int bn = 0; bn < NBN; ++bn) {
    f32x4 p = __builtin_nontemporal_load(
        (const f32x4*)(partial + ((size_t)bn * M_N + row) * 16 + quad * 4));
    v += p;
  }
  if (quad == 0) {
    float4 bq = *(const float4*)b;
    float* o = out + (size_t)row * NCLS;
    *(float2*)o       = {v.x + bq.x, v.y + bq.y};
    *(float2*)(o + 2) = {v.z + bq.z, v.w + bq.w};
  } else if (quad == 1) {
    float4 bq = *(const float4*)(b + 4);
    float* o = out + (size_t)row * NCLS + 4;
    *(float2*)o       = {v.x + bq.x, v.y + bq.y};
    *(float2*)(o + 2) = {v.z + bq.z, v.w + bq.w};
  } else if (quad == 2) {
    *(float2*)(out + (size_t)row * NCLS + 8) = {v.x + b[8], v.y + b[9]};
  }
}

// ---- launch --------------------------------------------------------------

extern "C" void kernel_launch(void* const* d_in, const int* in_sizes, int n_in,
                              void* d_out, int out_size, void* d_ws, size_t ws_size,
                              hipStream_t stream) {
  const float* batches = (const float*)d_in[0];  // [16384,512]
  const float* centers = (const float*)d_in[1];  // [2048,512]
  const float* beta    = (const float*)d_in[2];  // [1,2048]
  const float* W       = (const float*)d_in[3];  // [10,2048]
  const float* bias    = (const float*)d_in[4];  // [10]
  float* out = (float*)d_out;                    // [16384,10]

  char* ws = (char*)d_ws;
  u16*  Abf = (u16*)ws;                                   // 16 MiB
  u16*  Bbf = (u16*)(ws + (size_t)M_N * DIM * 2);         // 2 MiB
  float* x2 = (float*)(ws + (size_t)(M_N + K_C) * DIM * 2);
  float* c2 = x2 + M_N;
  u16*  Wpm = (u16*)(c2 + K_C);                           // 64 KiB
  float* partial = (float*)((char*)Wpm + 16 * K_C * 2);   // 16.8 MiB

  prep<<<dim3(NPREP + 32), dim3(256), 0, stream>>>(
      (const float4*)batches, (const float4*)centers, W,
      (ushort4*)Abf, (ushort4*)Bbf, x2, c2, Wpm);
  rbf_main<<<dim3(NBN * NBM), dim3(256), 0, stream>>>(
      Abf, Bbf, x2, c2, beta, Wpm, partial);
  reduce_out<<<dim3(M_N / 64), dim3(256), 0, stream>>>(partial, bias, out);
}